// Round 1
// baseline (226.157 us; speedup 1.0000x reference)
//
#include <hip/hip_runtime.h>

// IF (integrate-and-fire) SNN forward scan.
// x: [T*B, C, H, W] fp32 viewed as [T=8, slice=4,194,304 floats]; out same shape.
// Per element n: mem=0.5*thr; for t: mem+=x[t][n]; sp=(mem>=thr)?thr:0; mem-=sp.
//
// Ladder (aggregate bench us; kernel ~= agg - 155):
// R1  one-shot f4, default VGPR=28         -> 243.8
// R2  ILP=2 + nt st                        -> 233.8
// R4  (ablation) normal loads              -> 258.6  (nt LOADS locked in)
// R9  forced 16-deep MLP                   -> 222.8
// R10 forced 32-deep, 1024 blk, 2 res/CU   -> 217.8  prior BEST
// R11 forced 48-deep (683 blk, imbalance)  -> 221.5
//
// R13 (this): attack the DRAM side instead of the CU side.
// Theory: R10 leaves 512 resident blocks x 16 slice-streams = 8192 concurrent
// DRAM row-streams ~ 2x the device's open-row capacity -> row-activate bound
// at ~4.3 TB/s (vs 6.5+ TB/s for the few-stream harness fills).
// Change: grid=256 persistent blocks (1/CU -> 4096 streams), each owning a
// CONTIGUOUS 64 KiB range per slice, processed in 8 chunk-iterations with a
// double-buffered 2x16-load pipeline (64 nt loads in flight/thread steady
// state) so per-CU outstanding bytes match R10 despite half the waves.

typedef float f4 __attribute__((ext_vector_type(4)));

constexpr int T_STEPS = 8;
constexpr int BLOCK   = 256;
constexpr int ILP     = 2;              // columns per thread per chunk
constexpr int GRID    = 256;            // 1 block per CU
constexpr int CHUNK   = BLOCK * ILP;    // 512 f4 per chunk per slice

__global__ __launch_bounds__(BLOCK, 2) void if_fwd_kernel(
    const f4* __restrict__ x,
    const float* __restrict__ thresh,
    f4* __restrict__ out,
    int stride4)   // float4s per timestep slice (1,048,576)
{
    // Each block owns a contiguous [range0, range0 + per_block) window of
    // every slice; iterates it in CHUNK-sized steps (sequential streams).
    const int per_block = stride4 / GRID;            // 4096 f4 = 64 KiB
    const int range0    = blockIdx.x * per_block;
    const int niter     = per_block / CHUNK;         // 8

    const float thr = thresh[0];      // wave-uniform -> scalar load
    const float h   = 0.5f * thr;

    f4 bufA[T_STEPS][ILP];
    f4 bufB[T_STEPS][ILP];

    // Issue 16 independent nt loads for chunk `it` into buf.
    auto issue = [&](f4 (&buf)[T_STEPS][ILP], int it) {
        const int i0 = range0 + it * CHUNK + (int)threadIdx.x;
#pragma unroll
        for (int t = 0; t < T_STEPS; ++t) {
#pragma unroll
            for (int j = 0; j < ILP; ++j) {
                buf[t][j] = __builtin_nontemporal_load(
                    x + (size_t)t * stride4 + i0 + j * BLOCK);
            }
        }
    };

    // Run the 8-step IF scan on chunk `it` from buf; nt-store spikes.
    auto consume = [&](f4 (&buf)[T_STEPS][ILP], int it) {
        const int i0 = range0 + it * CHUNK + (int)threadIdx.x;
        f4 m[ILP];
#pragma unroll
        for (int j = 0; j < ILP; ++j) {
            m[j] = (f4){h, h, h, h};
        }
#pragma unroll
        for (int t = 0; t < T_STEPS; ++t) {
#pragma unroll
            for (int j = 0; j < ILP; ++j) {
                m[j] += buf[t][j];
                f4 s;
#pragma unroll
                for (int k = 0; k < 4; ++k) {
                    s[k] = (m[j][k] >= thr) ? thr : 0.0f;
                }
                m[j] -= s;
                __builtin_nontemporal_store(
                    s, out + (size_t)t * stride4 + i0 + j * BLOCK);
            }
        }
    };

    // Prologue: fill both buffers -> 32 loads in flight before first consume.
    issue(bufA, 0);
    __builtin_amdgcn_sched_barrier(0);
    issue(bufB, 1);
    __builtin_amdgcn_sched_barrier(0);

    // Steady state: consume oldest buffer, immediately refill it two chunks
    // ahead -> per-thread in-flight depth stays at 32 nt loads while the
    // other buffer's consume runs.
    for (int it = 0; it < niter; it += 2) {
        consume(bufA, it);
        if (it + 2 < niter) {
            issue(bufA, it + 2);
            __builtin_amdgcn_sched_barrier(0);
        }
        consume(bufB, it + 1);
        if (it + 3 < niter) {
            issue(bufB, it + 3);
            __builtin_amdgcn_sched_barrier(0);
        }
    }
}

extern "C" void kernel_launch(void* const* d_in, const int* in_sizes, int n_in,
                              void* d_out, int out_size, void* d_ws, size_t ws_size,
                              hipStream_t stream) {
    const float* x      = (const float*)d_in[0];   // [T*B, C, H, W] fp32
    const float* thresh = (const float*)d_in[1];   // scalar threshold (1 elem)
    float* out          = (float*)d_out;

    const int total   = in_sizes[0];       // 33,554,432
    const int stride  = total / T_STEPS;   // 4,194,304 elems per slice
    const int stride4 = stride / 4;        // 1,048,576 float4s per slice

    dim3 block(BLOCK);
    dim3 grid(GRID);                       // 256 persistent blocks, 1 per CU
    if_fwd_kernel<<<grid, block, 0, stream>>>(
        (const f4*)x, thresh, (f4*)out, stride4);
}

// Round 2
// 216.816 us; speedup vs baseline: 1.0431x; 1.0431x over previous
//
#include <hip/hip_runtime.h>

// IF (integrate-and-fire) SNN forward scan.
// x: [T*B, C, H, W] fp32 viewed as [T=8, slice=4,194,304 floats]; out same shape.
// Per element n: mem=0.5*thr; for t: mem+=x[t][n]; sp=(mem>=thr)?thr:0; mem-=sp.
//
// Final ladder (aggregate bench us; kernel ~= agg - 155):
// R1  one-shot f4, default VGPR=28         -> 243.8  (kernel 90)
// R2  ILP=2 + nt st (VGPR 32)              -> 233.8
// R3  persistent + nt ld/st                -> 238.9
// R4  R3 w/ normal loads                   -> 258.6  (nt LOADS = +25%, locked in)
// R5  SW pipeline (flattened at VGPR 32)   -> 235.6
// R7  forced  8-deep MLP (sched_barrier)   -> 232.5
// R8  LDS staging (global_load_lds)        -> 246.5  REGRESSED
// R9  forced 16-deep (48 KiB/CU outst.)    -> 222.8
// R10 forced 32-deep (64 KiB/CU outst.)    -> 217.8  BEST
// R11 forced 48-deep (96 KiB/CU, 683 blk)  -> 221.5  REGRESSED (knee / imbalance)
// R13 1 blk/CU dbuf contiguous (4096 strm) -> 226.2  REGRESSED
//     (stream-count theory killed: TLP loss > row-locality gain; and
//      streams/block=16 is intrinsic — the recurrence couples all 8 t-slices)
//
// ROOT CAUSE of the whole session: the compiler's default max-occupancy
// register budget (VGPR=32) silently serialized the load stream in every
// naive variant. Fix = launch_bounds VGPR headroom + sched_barrier(0) to pin
// N independent nt loads in distinct dest registers. Depth knee at 32.
// Residual gap to the 43-us copy roofline (~4.3 vs 6.3 TB/s) is
// pattern-intrinsic: 16 live 16-MiB-strided streams/block x 512 resident
// blocks ~ 8K concurrent DRAM row-streams -> row-activate-bound latency ~2x
// a contiguous copy; no CU-side lever moved it (structure, LDS, contiguity,
// resident-block count all tested and neutral/regressed).
//
// R14 = exact revert to R10 (measured optimum).

typedef float f4 __attribute__((ext_vector_type(4)));

constexpr int T_STEPS = 8;
constexpr int BLOCK   = 256;
constexpr int ILP     = 4;      // four n-columns per thread -> 32 loads in flight

__global__ __launch_bounds__(BLOCK, 2) void if_fwd_kernel(
    const f4* __restrict__ x,
    const float* __restrict__ thresh,
    f4* __restrict__ out,
    int stride4)   // float4s per timestep slice (1,048,576)
{
    const int i0 = blockIdx.x * (BLOCK * ILP) + threadIdx.x;

    const float thr = thresh[0];      // wave-uniform -> scalar load
    const float h   = 0.5f * thr;

    // 32 independent nt loads; sched_barrier(0) pins them all before any
    // consumption -> 32 distinct f4 dests (128 VGPRs), 512 B in flight/thread.
    f4 xt[T_STEPS][ILP];
#pragma unroll
    for (int t = 0; t < T_STEPS; ++t) {
#pragma unroll
        for (int j = 0; j < ILP; ++j) {
            xt[t][j] = __builtin_nontemporal_load(
                x + (size_t)t * stride4 + i0 + j * BLOCK);
        }
    }
    __builtin_amdgcn_sched_barrier(0);

    f4 m[ILP];
#pragma unroll
    for (int j = 0; j < ILP; ++j) {
        m[j] = (f4){h, h, h, h};
    }

#pragma unroll
    for (int t = 0; t < T_STEPS; ++t) {
#pragma unroll
        for (int j = 0; j < ILP; ++j) {
            m[j] += xt[t][j];
            f4 s;
#pragma unroll
            for (int k = 0; k < 4; ++k) {
                s[k] = (m[j][k] >= thr) ? thr : 0.0f;
            }
            m[j] -= s;
            __builtin_nontemporal_store(
                s, out + (size_t)t * stride4 + i0 + j * BLOCK);
        }
    }
}

extern "C" void kernel_launch(void* const* d_in, const int* in_sizes, int n_in,
                              void* d_out, int out_size, void* d_ws, size_t ws_size,
                              hipStream_t stream) {
    const float* x      = (const float*)d_in[0];   // [T*B, C, H, W] fp32
    const float* thresh = (const float*)d_in[1];   // scalar threshold (1 elem)
    float* out          = (float*)d_out;

    const int total   = in_sizes[0];       // 33,554,432
    const int stride  = total / T_STEPS;   // 4,194,304 elems per slice
    const int stride4 = stride / 4;        // 1,048,576 float4s per slice

    dim3 block(BLOCK);
    dim3 grid(stride4 / (BLOCK * ILP));    // 1024 blocks = 4 per CU, balanced
    if_fwd_kernel<<<grid, block, 0, stream>>>(
        (const f4*)x, thresh, (f4*)out, stride4);
}